// Round 1
// baseline (193.201 us; speedup 1.0000x reference)
//
#include <hip/hip_runtime.h>
#include <math.h>

// Top-8 (sorted descending) along last axis of (1024, 256, 128) fp32.
// One thread per 128-element row; LDS staging for coalesced global reads.

#define RPB     256            // rows per block == threads per block
#define NC      128            // columns per row
#define CHUNK   32             // columns staged per LDS chunk
#define NCHUNKS (NC / CHUNK)   // 4

__global__ __launch_bounds__(RPB) void topk8_kernel(const float* __restrict__ x,
                                                    float* __restrict__ out) {
    // +1 pad -> LDS row stride 33 floats: reads lds[t][j] hit bank (t+j)%32
    // (2-way alias across 64 lanes, free); float4 writes ~2-way as well.
    __shared__ float lds[RPB][CHUNK + 1];

    const int  t       = threadIdx.x;
    const long rowBase = (long)blockIdx.x * RPB;
    const float* xb    = x + rowBase * NC;

    float s0 = -INFINITY, s1 = -INFINITY, s2 = -INFINITY, s3 = -INFINITY;
    float s4 = -INFINITY, s5 = -INFINITY, s6 = -INFINITY, s7 = -INFINITY;

    for (int c = 0; c < NCHUNKS; ++c) {
        if (c) __syncthreads();   // protect previous chunk's readers

        // Stage 256 rows x 32 cols = 2048 float4 / 8 per thread, coalesced:
        // consecutive lanes -> consecutive float4 within a row segment.
        #pragma unroll
        for (int k = 0; k < 8; ++k) {
            const int f  = t + RPB * k;   // float4 slot in tile [0, 2048)
            const int rl = f >> 3;        // local row   [0, 256)
            const int c4 = f & 7;         // float4 slot within 32-col chunk
            const float4 v = *reinterpret_cast<const float4*>(
                xb + (long)rl * NC + c * CHUNK + c4 * 4);
            float* dst = &lds[rl][c4 * 4];
            dst[0] = v.x; dst[1] = v.y; dst[2] = v.z; dst[3] = v.w;
        }
        __syncthreads();

        // Branchless sorted-insert of each staged element into s0..s7.
        #pragma unroll
        for (int j = 0; j < CHUNK; ++j) {
            float v = lds[t][j];
            float m;
            m = fmaxf(s0, v); v = fminf(s0, v); s0 = m;
            m = fmaxf(s1, v); v = fminf(s1, v); s1 = m;
            m = fmaxf(s2, v); v = fminf(s2, v); s2 = m;
            m = fmaxf(s3, v); v = fminf(s3, v); s3 = m;
            m = fmaxf(s4, v); v = fminf(s4, v); s4 = m;
            m = fmaxf(s5, v); v = fminf(s5, v); s5 = m;
            m = fmaxf(s6, v); v = fminf(s6, v); s6 = m;
            m = fmaxf(s7, v); v = fminf(s7, v); s7 = m;
        }
    }

    // Row r writes out[r*8 .. r*8+7], two float4 stores (coalesced across lanes).
    float* op = out + (rowBase + t) * 8;
    reinterpret_cast<float4*>(op)[0] = make_float4(s0, s1, s2, s3);
    reinterpret_cast<float4*>(op)[1] = make_float4(s4, s5, s6, s7);
}

extern "C" void kernel_launch(void* const* d_in, const int* in_sizes, int n_in,
                              void* d_out, int out_size, void* d_ws, size_t ws_size,
                              hipStream_t stream) {
    const float* x  = (const float*)d_in[0];
    float* out      = (float*)d_out;
    const long total = (long)in_sizes[0];      // 1024*256*128
    const int  nrows = (int)(total / NC);      // 262144
    const int  blocks = nrows / RPB;           // 1024 (exact for this shape)
    topk8_kernel<<<blocks, RPB, 0, stream>>>(x, out);
}